// Round 2
// baseline (443.308 us; speedup 1.0000x reference)
//
#include <hip/hip_runtime.h>
#include <math.h>

#define Bz 32
#define Lz 2048
#define Hz 768
#define Tz 12
#define Ez 7
#define EMPTYIDX 6
#define NCOL 24              // T*2 logit columns per batch
#define NITEM (Bz * Tz)      // 384 (b,t) pairs
#define LCHUNK 128
#define NCHUNK 16            // Lz / LCHUNK

// ---------------- kernel 0: bin (b,t) pairs by module index e ----------------
__global__ void k0_compact(const int* __restrict__ midx,
                           int* __restrict__ off, int* __restrict__ items) {
    __shared__ int cnt[Ez];
    __shared__ int offs[Ez + 1];
    int tid = threadIdx.x;                 // 384 threads, one per (b,t)
    if (tid < Ez) cnt[tid] = 0;
    __syncthreads();
    int e = midx[tid];
    e = min(max(e, 0), Ez - 1);
    int r = atomicAdd(&cnt[e], 1);
    __syncthreads();
    if (tid == 0) {
        int acc = 0;
        for (int j = 0; j < Ez; ++j) { offs[j] = acc; acc += cnt[j]; }
        offs[Ez] = acc;
    }
    __syncthreads();
    items[offs[e] + r] = tid;
    if (tid <= Ez) off[tid] = offs[tid];
}

// ---------------- kernel 1a: cW partial dots, H split across blocks ----------
// grid = Ez(7) * ZC(3) * HC(16) = 336 blocks, 256 threads.
// W[e] 48h x 256z slab in registers (read from HBM exactly once). Partial for
// h-chunk hc stored to a DISJOINT buffer pc[hc][i][z] (plain coalesced store)
// -- no atomics, no memset dependency. Reduced over hc in k1b.
#define K1A_ZC 3
#define K1A_HB 48
#define K1A_HC 16
__global__ void k1a_cw(const float* __restrict__ seq, const float* __restrict__ W,
                       const int* __restrict__ turns,
                       const int* __restrict__ off, const int* __restrict__ items,
                       float* __restrict__ pc) {
    int bx = blockIdx.x;
    int e  = bx % Ez;
    int zc = (bx / Ez) % K1A_ZC;
    int hc = bx / (Ez * K1A_ZC);           // 0..15
    int z  = zc * 256 + threadIdx.x;       // 0..767
    int h0 = hc * K1A_HB;
    int off0 = off[e];
    int cnt  = off[e + 1] - off0;
    const float* Wb = W + ((size_t)e * Hz + h0) * Hz + z;
    float w[K1A_HB];
#pragma unroll
    for (int j = 0; j < K1A_HB; ++j) w[j] = Wb[(size_t)j * Hz];

    for (int n = 0; n < cnt; ++n) {
        int i  = items[off0 + n];          // wave-uniform in practice
        int b  = i / Tz;
        int st = turns[2 * i];
        st = min(max(st, 0), Lz - 1);
        const float* c = seq + ((size_t)(b * Lz + st)) * Hz + h0;
        float acc = 0.f;
#pragma unroll
        for (int j = 0; j < K1A_HB; ++j) acc = fmaf(c[j], w[j], acc);
        pc[((size_t)hc * NITEM + i) * Hz + z] = acc;   // disjoint -> plain store
    }
}

// ---------------- kernel 1b: reduce hc partials, v = cW * spanw --------------
__global__ void k1b_v(const float* __restrict__ pc, const float* __restrict__ spanw,
                      const int* __restrict__ midx, float* __restrict__ v) {
    int idx = blockIdx.x * 256 + threadIdx.x;   // 384*768 = 294912
    int i = idx / Hz;
    int z = idx - i * Hz;
    float cw = 0.f;
#pragma unroll
    for (int hc = 0; hc < K1A_HC; ++hc)
        cw += pc[((size_t)hc * NITEM + i) * Hz + z];
    int e = midx[i];
    e = min(max(e, 0), Ez - 1);
    int b = i / Tz, t = i - b * Tz;
    size_t vb = ((size_t)(b * NCOL + t * 2)) * Hz + z;
    v[vb]      = cw * spanw[(e * Hz + z) * 2 + 0];
    v[vb + Hz] = cw * spanw[(e * Hz + z) * 2 + 1];
}

// ---------------- kernel 2: logits GEMM + chunk logsumexp + picked -----------
// grid = Bz*NCHUNK = 512 blocks, 256 threads.
// Row-per-thread formulation: thread owns one seq row (r = tid&127) and ALL 24
// output columns in registers; tid>>7 selects which 32-wide k-half the thread
// accumulates (wave-uniform via readfirstlane). Per 64-k phase each thread does
// 8 ds_read_b128 of its own row (XOR-swizzled staging -> the 64 lanes of a
// wave spread over all 8 LDS bank-groups, minimum 8-cyc service) feeding 768
// fully-unrolled FMAs. ALL loop indices are compile-time constants after
// unrolling -> acc[24]/a[32]/g[8] live in VGPRs (round-1 spill was caused by
// "#pragma unroll 2" making acc runtime-indexed -> scratch, 194 MB of spill
// writes). V addresses are wave-uniform -> SMEM-pipe s_load (SGPR operand of
// v_fmac) or worst-case L1-broadcast VMEM. picked (old k3) fused in epilogue.
#define BKP 64               // k floats staged per phase (both halves)
#define NPH (Hz / BKP)       // 12
__global__ __launch_bounds__(256, 2)
void k2_logits(const float* __restrict__ seq, const float* __restrict__ v,
               const int* __restrict__ kps,
               float* __restrict__ pm, float* __restrict__ ps,
               float* __restrict__ picked) {
    int bx  = blockIdx.x;
    int b   = bx / NCHUNK;
    int ch  = bx % NCHUNK;
    int l0  = ch * LCHUNK;
    int tid = threadIdx.x;
    int r   = tid & (LCHUNK - 1);                       // row within chunk
    int kh  = __builtin_amdgcn_readfirstlane(tid >> 7); // k-half, wave-uniform

    __shared__ float at[LCHUNK][BKP];        // 32 KB, XOR-swizzled 16B groups
    // lg overlaid on at: at is dead once the k-loop finishes (guarded by a
    // __syncthreads before first lg write). Saves 12.8 KB -> 33.6 KB/block.
    float (*lg)[NCOL + 1] = reinterpret_cast<float (*)[NCOL + 1]>(&at[0][0]);
    __shared__ float redm[NCOL][4], reds[NCOL][4];
    __shared__ int   ksafe[NCOL];

    if (tid < NCOL) {                        // kps (B,T,2) -> b*24 + col
        int t0 = kps[b * NCOL + tid];
        ksafe[tid] = min(max(t0, 0), Lz - 1);
    }

    float acc[NCOL];
#pragma unroll
    for (int c = 0; c < NCOL; ++c) acc[c] = 0.f;

    const float* A = seq + ((size_t)b * Lz + l0) * Hz;
    const float* V = v + (size_t)b * NCOL * Hz;

    // prologue: phase-0 global loads into registers
    float4 g[8];
#pragma unroll
    for (int p = 0; p < 8; ++p) {
        int j = tid + p * 256, rr = j >> 4, c4 = j & 15;
        g[p] = *(const float4*)&A[(size_t)rr * Hz + c4 * 4];
    }

    for (int ph = 0; ph < NPH; ++ph) {
        __syncthreads();                      // prev compute done reading at
#pragma unroll
        for (int p = 0; p < 8; ++p) {         // swizzled stage: slot = c4 ^ (row&15)
            int j = tid + p * 256, rr = j >> 4, c4 = j & 15;
            *(float4*)&at[rr][((c4 ^ (rr & 15)) << 2)] = g[p];
        }
        __syncthreads();
        if (ph + 1 < NPH) {                   // issue next-phase loads early;
#pragma unroll                                 // HBM latency hides under compute
            for (int p = 0; p < 8; ++p) {
                int j = tid + p * 256, rr = j >> 4, c4 = j & 15;
                g[p] = *(const float4*)&A[(size_t)rr * Hz + (ph + 1) * BKP + c4 * 4];
            }
        }
        // this thread's 32 A-floats for its k-half, read once, reused x24 cols
        float a[32];
#pragma unroll
        for (int q4 = 0; q4 < 8; ++q4) {
            int c4 = kh * 8 + q4;
            float4 x = *(const float4*)&at[r][((c4 ^ (r & 15)) << 2)];
            a[q4 * 4 + 0] = x.x; a[q4 * 4 + 1] = x.y;
            a[q4 * 4 + 2] = x.z; a[q4 * 4 + 3] = x.w;
        }
        const float* Vp = V + ph * BKP + kh * 32;   // wave-uniform
#pragma unroll
        for (int c = 0; c < NCOL; ++c) {
            const float* vp = Vp + (size_t)c * Hz;
            float s0 = 0.f, s1 = 0.f, s2 = 0.f, s3 = 0.f;
#pragma unroll
            for (int q = 0; q < 32; q += 4) {
                s0 = fmaf(a[q + 0], vp[q + 0], s0);
                s1 = fmaf(a[q + 1], vp[q + 1], s1);
                s2 = fmaf(a[q + 2], vp[q + 2], s2);
                s3 = fmaf(a[q + 3], vp[q + 3], s3);
            }
            acc[c] += (s0 + s1) + (s2 + s3);
        }
    }

    // merge the two k-halves: rows r held by tid and tid+128.
    __syncthreads();                          // ALL waves done reading at -> lg safe
    if (kh == 1) {
#pragma unroll
        for (int c = 0; c < NCOL; ++c) lg[r][c] = acc[c];
    }
    __syncthreads();
    if (kh == 0) {
#pragma unroll
        for (int c = 0; c < NCOL; ++c) { acc[c] += lg[r][c]; lg[r][c] = acc[c]; }
        // fused k3: the thread owning the target row emits the picked logit
        int grow = l0 + r;
#pragma unroll
        for (int c = 0; c < NCOL; ++c)
            if (ksafe[c] == grow) picked[b * NCOL + c] = acc[c];
    }
    __syncthreads();

    // chunk logsumexp partials: 96 threads = 24 cols x 4 row-quarters
    if (tid < 96) {
        int c = tid >> 2, rg = tid & 3;
        float m = lg[rg * 32][c];
        for (int rr = rg * 32 + 1; rr < rg * 32 + 32; ++rr)
            m = fmaxf(m, lg[rr][c]);
        float s = 0.f;
        for (int rr = rg * 32; rr < rg * 32 + 32; ++rr)
            s += expf(lg[rr][c] - m);
        redm[c][rg] = m; reds[c][rg] = s;
    }
    __syncthreads();
    if (tid < NCOL) {
        float m = redm[tid][0];
        for (int j = 1; j < 4; ++j) m = fmaxf(m, redm[tid][j]);
        float s = 0.f;
        for (int j = 0; j < 4; ++j) s += reds[tid][j] * expf(redm[tid][j] - m);
        pm[((size_t)b * NCOL + tid) * NCHUNK + ch] = m;
        ps[((size_t)b * NCOL + tid) * NCHUNK + ch] = s;
    }
}

// ---------------- kernel 4: combine partials -> ce -> masked-mean loss -------
__global__ void k4_final(const int* __restrict__ midx, const int* __restrict__ turns,
                         const int* __restrict__ kps,
                         const float* __restrict__ pm, const float* __restrict__ ps,
                         const float* __restrict__ picked, float* __restrict__ out) {
    int tid = threadIdx.x;                 // 384 threads, one per (b,t)
    int i = tid;
    int b = i / Tz, t = i % Tz;
    int e = midx[i];
    float modm  = (e != EMPTYIDX) ? 1.f : 0.f;
    float tmask = (turns[2 * i] >= 0) ? 1.f : 0.f;
    float ce[2];
#pragma unroll
    for (int k = 0; k < 2; ++k) {
        int c = t * 2 + k;
        const float* pmr = pm + ((size_t)b * NCOL + c) * NCHUNK;
        const float* psr = ps + ((size_t)b * NCOL + c) * NCHUNK;
        float m = pmr[0];
        for (int chn = 1; chn < NCHUNK; ++chn) m = fmaxf(m, pmr[chn]);
        float s = 0.f;
        for (int chn = 0; chn < NCHUNK; ++chn) s += psr[chn] * expf(pmr[chn] - m);
        float lse = m + logf(s);
        int tgt = kps[2 * i + k];
        ce[k] = (tgt >= 0) ? (lse - picked[b * NCOL + c]) : 0.f;
    }
    float contrib = 0.5f * (ce[0] + ce[1]) * modm * tmask;

    __shared__ float wsum[6], wmask[6];
    float sl = contrib, sm = tmask;
    for (int o = 32; o > 0; o >>= 1) {
        sl += __shfl_down(sl, o, 64);
        sm += __shfl_down(sm, o, 64);
    }
    int w = tid >> 6, lane = tid & 63;
    if (lane == 0) { wsum[w] = sl; wmask[w] = sm; }
    __syncthreads();
    if (tid == 0) {
        float a = 0.f, mk = 0.f;
        for (int ww = 0; ww < 6; ++ww) { a += wsum[ww]; mk += wmask[ww]; }
        out[0] = a / mk;
    }
}

extern "C" void kernel_launch(void* const* d_in, const int* in_sizes, int n_in,
                              void* d_out, int out_size, void* d_ws, size_t ws_size,
                              hipStream_t stream) {
    const float* seq   = (const float*)d_in[0];  // (32,2048,768)
    const float* W     = (const float*)d_in[1];  // (7,768,768)
    const float* spanw = (const float*)d_in[2];  // (7,768,2)
    const int*   turns = (const int*)d_in[3];    // (32,12,2)
    const int*   kps   = (const int*)d_in[4];    // (32,12,2)
    const int*   midx  = (const int*)d_in[5];    // (32,12)
    float* out = (float*)d_out;

    char* ws = (char*)d_ws;
    int*   off    = (int*)(ws + 0);                              // 8 ints
    int*   items  = (int*)(ws + 256);                            // 384 ints
    float* pc     = (float*)(ws + 2048);                         // 16*384*768 f32 = 18,874,368 B
    float* v      = (float*)(ws + 2048 + 18874368);              // 32*24*768 f32 =  2,359,296 B
    float* pm     = (float*)(ws + 2048 + 18874368 + 2359296);            // 49,152 B
    float* ps     = (float*)(ws + 2048 + 18874368 + 2359296 + 49152);    // 49,152 B
    float* picked = (float*)(ws + 2048 + 18874368 + 2359296 + 98304);    //  1,536 B

    hipLaunchKernelGGL(k0_compact, dim3(1), dim3(NITEM), 0, stream, midx, off, items);
    hipLaunchKernelGGL(k1a_cw, dim3(Ez * K1A_ZC * K1A_HC), dim3(256), 0, stream,
                       seq, W, turns, off, items, pc);
    hipLaunchKernelGGL(k1b_v, dim3((NITEM * Hz) / 256), dim3(256), 0, stream,
                       pc, spanw, midx, v);
    hipLaunchKernelGGL(k2_logits, dim3(Bz * NCHUNK), dim3(256), 0, stream,
                       seq, v, kps, pm, ps, picked);
    hipLaunchKernelGGL(k4_final, dim3(1), dim3(NITEM), 0, stream,
                       midx, turns, kps, pm, ps, picked, out);
}

// Round 4
// 409.729 us; speedup vs baseline: 1.0820x; 1.0820x over previous
//
#include <hip/hip_runtime.h>
#include <math.h>

#define Bz 32
#define Lz 2048
#define Hz 768
#define Tz 12
#define Ez 7
#define EMPTYIDX 6
#define NCOL 24              // T*2 logit columns per batch
#define NITEM (Bz * Tz)      // 384 (b,t) pairs
#define LCHUNK 128
#define NCHUNK 16            // Lz / LCHUNK

// ---------------- kernel 0: bin (b,t) pairs by module index e ----------------
__global__ void k0_compact(const int* __restrict__ midx,
                           int* __restrict__ off, int* __restrict__ items) {
    __shared__ int cnt[Ez];
    __shared__ int offs[Ez + 1];
    int tid = threadIdx.x;                 // 384 threads, one per (b,t)
    if (tid < Ez) cnt[tid] = 0;
    __syncthreads();
    int e = midx[tid];
    e = min(max(e, 0), Ez - 1);
    int r = atomicAdd(&cnt[e], 1);
    __syncthreads();
    if (tid == 0) {
        int acc = 0;
        for (int j = 0; j < Ez; ++j) { offs[j] = acc; acc += cnt[j]; }
        offs[Ez] = acc;
    }
    __syncthreads();
    items[offs[e] + r] = tid;
    if (tid <= Ez) off[tid] = offs[tid];
}

// ---------------- kernel 1a: cW partial dots, H split across blocks ----------
#define K1A_ZC 3
#define K1A_HB 48
#define K1A_HC 16
__global__ void k1a_cw(const float* __restrict__ seq, const float* __restrict__ W,
                       const int* __restrict__ turns,
                       const int* __restrict__ off, const int* __restrict__ items,
                       float* __restrict__ pc) {
    int bx = blockIdx.x;
    int e  = bx % Ez;
    int zc = (bx / Ez) % K1A_ZC;
    int hc = bx / (Ez * K1A_ZC);           // 0..15
    int z  = zc * 256 + threadIdx.x;       // 0..767
    int h0 = hc * K1A_HB;
    int off0 = off[e];
    int cnt  = off[e + 1] - off0;
    const float* Wb = W + ((size_t)e * Hz + h0) * Hz + z;
    float w[K1A_HB];
#pragma unroll
    for (int j = 0; j < K1A_HB; ++j) w[j] = Wb[(size_t)j * Hz];

    for (int n = 0; n < cnt; ++n) {
        int i  = items[off0 + n];          // wave-uniform in practice
        int b  = i / Tz;
        int st = turns[2 * i];
        st = min(max(st, 0), Lz - 1);
        const float* c = seq + ((size_t)(b * Lz + st)) * Hz + h0;
        float acc = 0.f;
#pragma unroll
        for (int j = 0; j < K1A_HB; ++j) acc = fmaf(c[j], w[j], acc);
        pc[((size_t)hc * NITEM + i) * Hz + z] = acc;   // disjoint -> plain store
    }
}

// ---------------- kernel 1b: reduce hc partials, v = cW * spanw --------------
__global__ void k1b_v(const float* __restrict__ pc, const float* __restrict__ spanw,
                      const int* __restrict__ midx, float* __restrict__ v) {
    int idx = blockIdx.x * 256 + threadIdx.x;   // 384*768 = 294912
    int i = idx / Hz;
    int z = idx - i * Hz;
    float cw = 0.f;
#pragma unroll
    for (int hc = 0; hc < K1A_HC; ++hc)
        cw += pc[((size_t)hc * NITEM + i) * Hz + z];
    int e = midx[i];
    e = min(max(e, 0), Ez - 1);
    int b = i / Tz, t = i - b * Tz;
    size_t vb = ((size_t)(b * NCOL + t * 2)) * Hz + z;
    v[vb]      = cw * spanw[(e * Hz + z) * 2 + 0];
    v[vb + Hz] = cw * spanw[(e * Hz + z) * 2 + 1];
}

// ---------------- kernel 2: logits GEMM + chunk logsumexp + picked -----------
// Row-per-thread, k-half split. ALL per-thread state is NAMED scalars/float4
// (rule #20: SROA demotes any locally-indexed array to scratch BEFORE unroll;
// r1/r2 measured VGPR_Count=52 + 194MB scratch traffic from exactly this).
// Named values cannot be demoted. A staged via XOR-swizzled LDS (8 b128/phase
// per thread); V read as wave-uniform global float4 broadcasts (L1/L2
// resident); picked fused in epilogue.
#define BKP 64               // k floats staged per phase (both halves)
#define NPH (Hz / BKP)       // 12

typedef float4 F4;

__device__ __forceinline__ float dot32(const float* __restrict__ vp,
    F4 a0, F4 a1, F4 a2, F4 a3, F4 a4, F4 a5, F4 a6, F4 a7) {
    const F4* vq = (const F4*)vp;
    F4 q0 = vq[0], q1 = vq[1], q2 = vq[2], q3 = vq[3],
       q4 = vq[4], q5 = vq[5], q6 = vq[6], q7 = vq[7];
    float s0 = 0.f, s1 = 0.f, s2 = 0.f, s3 = 0.f;
    s0 = fmaf(a0.x, q0.x, s0); s1 = fmaf(a0.y, q0.y, s1);
    s2 = fmaf(a0.z, q0.z, s2); s3 = fmaf(a0.w, q0.w, s3);
    s0 = fmaf(a1.x, q1.x, s0); s1 = fmaf(a1.y, q1.y, s1);
    s2 = fmaf(a1.z, q1.z, s2); s3 = fmaf(a1.w, q1.w, s3);
    s0 = fmaf(a2.x, q2.x, s0); s1 = fmaf(a2.y, q2.y, s1);
    s2 = fmaf(a2.z, q2.z, s2); s3 = fmaf(a2.w, q2.w, s3);
    s0 = fmaf(a3.x, q3.x, s0); s1 = fmaf(a3.y, q3.y, s1);
    s2 = fmaf(a3.z, q3.z, s2); s3 = fmaf(a3.w, q3.w, s3);
    s0 = fmaf(a4.x, q4.x, s0); s1 = fmaf(a4.y, q4.y, s1);
    s2 = fmaf(a4.z, q4.z, s2); s3 = fmaf(a4.w, q4.w, s3);
    s0 = fmaf(a5.x, q5.x, s0); s1 = fmaf(a5.y, q5.y, s1);
    s2 = fmaf(a5.z, q5.z, s2); s3 = fmaf(a5.w, q5.w, s3);
    s0 = fmaf(a6.x, q6.x, s0); s1 = fmaf(a6.y, q6.y, s1);
    s2 = fmaf(a6.z, q6.z, s2); s3 = fmaf(a6.w, q6.w, s3);
    s0 = fmaf(a7.x, q7.x, s0); s1 = fmaf(a7.y, q7.y, s1);
    s2 = fmaf(a7.z, q7.z, s2); s3 = fmaf(a7.w, q7.w, s3);
    return (s0 + s1) + (s2 + s3);
}

#define C_LIST(X) X(0) X(1) X(2) X(3) X(4) X(5) X(6) X(7) X(8) X(9) X(10) X(11) \
                  X(12) X(13) X(14) X(15) X(16) X(17) X(18) X(19) X(20) X(21) X(22) X(23)

__global__ __launch_bounds__(256, 2)
void k2_logits(const float* __restrict__ seq, const float* __restrict__ v,
               const int* __restrict__ kps,
               float* __restrict__ pm, float* __restrict__ ps,
               float* __restrict__ picked) {
    int bx  = blockIdx.x;
    int b   = bx / NCHUNK;
    int ch  = bx % NCHUNK;
    int l0  = ch * LCHUNK;
    int tid = threadIdx.x;
    int r   = tid & (LCHUNK - 1);                       // row within chunk
    int kh  = __builtin_amdgcn_readfirstlane(tid >> 7); // k-half, wave-uniform

    __shared__ float at[LCHUNK][BKP];        // 32 KB, XOR-swizzled 16B groups
    __shared__ float lg[LCHUNK][NCOL + 1];   // merged logits
    __shared__ float redm[NCOL][4], reds[NCOL][4];
    __shared__ int   ksafe[NCOL];

    if (tid < NCOL) {
        int t0 = kps[b * NCOL + tid];
        ksafe[tid] = min(max(t0, 0), Lz - 1);
    }

#define DECL_ACC(n) float c##n = 0.f;
    C_LIST(DECL_ACC)
#undef DECL_ACC

    const float* A = seq + ((size_t)b * Lz + l0) * Hz;
    const float* V = v + (size_t)b * NCOL * Hz;

    // staging geometry: thread (rb, cq) stages rows rb+16p, 16B group cq,
    // into swizzled slot (cq ^ (rb&15)); slot is p-invariant since 16p = 0 mod 16.
    int rb   = tid >> 4;                   // 0..15
    int cq   = tid & 15;                   // 16B group index (renamed: c4 collided with acc c4)
    int slot = ((cq ^ (rb & 15)) << 2);
    const float* Ab0 = A + (size_t)rb * Hz + (cq << 2);
    float* Sb = &at[0][0] + rb * BKP + slot;          // +1024 floats per p-step

    // phase-invariant LDS read addresses for this thread's 32 A-floats
    int rx = r & 15;
    const float* arow = &at[r][0];
    const float* ap0 = arow + (((kh * 8 + 0) ^ rx) << 2);
    const float* ap1 = arow + (((kh * 8 + 1) ^ rx) << 2);
    const float* ap2 = arow + (((kh * 8 + 2) ^ rx) << 2);
    const float* ap3 = arow + (((kh * 8 + 3) ^ rx) << 2);
    const float* ap4 = arow + (((kh * 8 + 4) ^ rx) << 2);
    const float* ap5 = arow + (((kh * 8 + 5) ^ rx) << 2);
    const float* ap6 = arow + (((kh * 8 + 6) ^ rx) << 2);
    const float* ap7 = arow + (((kh * 8 + 7) ^ rx) << 2);

    F4 g0, g1, g2, g3, g4, g5, g6, g7;
#define LOADG(KOFF) do { const float* Ap_ = Ab0 + (KOFF);            \
        g0 = *(const F4*)&Ap_[0 * 16 * Hz];                          \
        g1 = *(const F4*)&Ap_[1 * 16 * Hz];                          \
        g2 = *(const F4*)&Ap_[2 * 16 * Hz];                          \
        g3 = *(const F4*)&Ap_[3 * 16 * Hz];                          \
        g4 = *(const F4*)&Ap_[4 * 16 * Hz];                          \
        g5 = *(const F4*)&Ap_[5 * 16 * Hz];                          \
        g6 = *(const F4*)&Ap_[6 * 16 * Hz];                          \
        g7 = *(const F4*)&Ap_[7 * 16 * Hz]; } while (0)

    LOADG(0);                              // prologue: phase-0 loads

#pragma unroll 1
    for (int ph = 0; ph < NPH; ++ph) {
        __syncthreads();                   // prev compute done reading at
        *(F4*)&Sb[0 * 1024] = g0;  *(F4*)&Sb[1 * 1024] = g1;
        *(F4*)&Sb[2 * 1024] = g2;  *(F4*)&Sb[3 * 1024] = g3;
        *(F4*)&Sb[4 * 1024] = g4;  *(F4*)&Sb[5 * 1024] = g5;
        *(F4*)&Sb[6 * 1024] = g6;  *(F4*)&Sb[7 * 1024] = g7;
        __syncthreads();
        if (ph + 1 < NPH) LOADG((ph + 1) * BKP);   // hide HBM under compute

        F4 a0 = *(const F4*)ap0, a1 = *(const F4*)ap1,
           a2 = *(const F4*)ap2, a3 = *(const F4*)ap3,
           a4 = *(const F4*)ap4, a5 = *(const F4*)ap5,
           a6 = *(const F4*)ap6, a7 = *(const F4*)ap7;

        const float* Vp = V + ph * BKP + kh * 32;   // wave-uniform
#define DO_COL(n) c##n += dot32(Vp + (n) * Hz, a0, a1, a2, a3, a4, a5, a6, a7);
        C_LIST(DO_COL)
#undef DO_COL
    }
#undef LOADG

    // merge the two k-halves: rows r held by tid and tid+128
    __syncthreads();
    if (kh == 1) {
#define ST_LG(n) lg[r][n] = c##n;
        C_LIST(ST_LG)
#undef ST_LG
    }
    __syncthreads();
    if (kh == 0) {
        int grow = l0 + r;
#define MG_LG(n) { c##n += lg[r][n]; lg[r][n] = c##n;                 \
                   if (ksafe[n] == grow) picked[b * NCOL + (n)] = c##n; }
        C_LIST(MG_LG)
#undef MG_LG
    }
    __syncthreads();

    // chunk logsumexp partials: 96 threads = 24 cols x 4 row-quarters
    if (tid < 96) {
        int c = tid >> 2, rg = tid & 3;
        float m = lg[rg * 32][c];
        for (int rr = rg * 32 + 1; rr < rg * 32 + 32; ++rr)
            m = fmaxf(m, lg[rr][c]);
        float s = 0.f;
        for (int rr = rg * 32; rr < rg * 32 + 32; ++rr)
            s += expf(lg[rr][c] - m);
        redm[c][rg] = m; reds[c][rg] = s;
    }
    __syncthreads();
    if (tid < NCOL) {
        float m = redm[tid][0];
        for (int j = 1; j < 4; ++j) m = fmaxf(m, redm[tid][j]);
        float s = 0.f;
        for (int j = 0; j < 4; ++j) s += reds[tid][j] * expf(redm[tid][j] - m);
        pm[((size_t)b * NCOL + tid) * NCHUNK + ch] = m;
        ps[((size_t)b * NCOL + tid) * NCHUNK + ch] = s;
    }
}

// ---------------- kernel 4: combine partials -> ce -> masked-mean loss -------
__global__ void k4_final(const int* __restrict__ midx, const int* __restrict__ turns,
                         const int* __restrict__ kps,
                         const float* __restrict__ pm, const float* __restrict__ ps,
                         const float* __restrict__ picked, float* __restrict__ out) {
    int tid = threadIdx.x;                 // 384 threads, one per (b,t)
    int i = tid;
    int b = i / Tz, t = i % Tz;
    int e = midx[i];
    float modm  = (e != EMPTYIDX) ? 1.f : 0.f;
    float tmask = (turns[2 * i] >= 0) ? 1.f : 0.f;
    float ce[2];
#pragma unroll
    for (int k = 0; k < 2; ++k) {
        int c = t * 2 + k;
        const float* pmr = pm + ((size_t)b * NCOL + c) * NCHUNK;
        const float* psr = ps + ((size_t)b * NCOL + c) * NCHUNK;
        float m = pmr[0];
        for (int chn = 1; chn < NCHUNK; ++chn) m = fmaxf(m, pmr[chn]);
        float s = 0.f;
        for (int chn = 0; chn < NCHUNK; ++chn) s += psr[chn] * expf(pmr[chn] - m);
        float lse = m + logf(s);
        int tgt = kps[2 * i + k];
        ce[k] = (tgt >= 0) ? (lse - picked[b * NCOL + c]) : 0.f;
    }
    float contrib = 0.5f * (ce[0] + ce[1]) * modm * tmask;

    __shared__ float wsum[6], wmask[6];
    float sl = contrib, sm = tmask;
    for (int o = 32; o > 0; o >>= 1) {
        sl += __shfl_down(sl, o, 64);
        sm += __shfl_down(sm, o, 64);
    }
    int w = tid >> 6, lane = tid & 63;
    if (lane == 0) { wsum[w] = sl; wmask[w] = sm; }
    __syncthreads();
    if (tid == 0) {
        float a = 0.f, mk = 0.f;
        for (int ww = 0; ww < 6; ++ww) { a += wsum[ww]; mk += wmask[ww]; }
        out[0] = a / mk;
    }
}

extern "C" void kernel_launch(void* const* d_in, const int* in_sizes, int n_in,
                              void* d_out, int out_size, void* d_ws, size_t ws_size,
                              hipStream_t stream) {
    const float* seq   = (const float*)d_in[0];  // (32,2048,768)
    const float* W     = (const float*)d_in[1];  // (7,768,768)
    const float* spanw = (const float*)d_in[2];  // (7,768,2)
    const int*   turns = (const int*)d_in[3];    // (32,12,2)
    const int*   kps   = (const int*)d_in[4];    // (32,12,2)
    const int*   midx  = (const int*)d_in[5];    // (32,12)
    float* out = (float*)d_out;

    char* ws = (char*)d_ws;
    int*   off    = (int*)(ws + 0);                              // 8 ints
    int*   items  = (int*)(ws + 256);                            // 384 ints
    float* pc     = (float*)(ws + 2048);                         // 16*384*768 f32 = 18,874,368 B
    float* v      = (float*)(ws + 2048 + 18874368);              // 32*24*768 f32 =  2,359,296 B
    float* pm     = (float*)(ws + 2048 + 18874368 + 2359296);            // 49,152 B
    float* ps     = (float*)(ws + 2048 + 18874368 + 2359296 + 49152);    // 49,152 B
    float* picked = (float*)(ws + 2048 + 18874368 + 2359296 + 98304);    //  1,536 B

    hipLaunchKernelGGL(k0_compact, dim3(1), dim3(NITEM), 0, stream, midx, off, items);
    hipLaunchKernelGGL(k1a_cw, dim3(Ez * K1A_ZC * K1A_HC), dim3(256), 0, stream,
                       seq, W, turns, off, items, pc);
    hipLaunchKernelGGL(k1b_v, dim3((NITEM * Hz) / 256), dim3(256), 0, stream,
                       pc, spanw, midx, v);
    hipLaunchKernelGGL(k2_logits, dim3(Bz * NCHUNK), dim3(256), 0, stream,
                       seq, v, kps, pm, ps, picked);
    hipLaunchKernelGGL(k4_final, dim3(1), dim3(NITEM), 0, stream,
                       midx, turns, kps, pm, ps, picked, out);
}

// Round 5
// 379.481 us; speedup vs baseline: 1.1682x; 1.0797x over previous
//
#include <hip/hip_runtime.h>
#include <math.h>

#define Bz 32
#define Lz 2048
#define Hz 768
#define Tz 12
#define Ez 7
#define EMPTYIDX 6
#define NCOL 24              // T*2 logit columns per batch
#define NITEM (Bz * Tz)      // 384 (b,t) pairs
#define LCHUNK 64
#define NCHUNK 32            // Lz / LCHUNK -> grid 1024 = 4 blocks/CU

// ---------------- kernel 0: bin (b,t) pairs by module index e ----------------
__global__ void k0_compact(const int* __restrict__ midx,
                           int* __restrict__ off, int* __restrict__ items) {
    __shared__ int cnt[Ez];
    __shared__ int offs[Ez + 1];
    int tid = threadIdx.x;                 // 384 threads, one per (b,t)
    if (tid < Ez) cnt[tid] = 0;
    __syncthreads();
    int e = midx[tid];
    e = min(max(e, 0), Ez - 1);
    int r = atomicAdd(&cnt[e], 1);
    __syncthreads();
    if (tid == 0) {
        int acc = 0;
        for (int j = 0; j < Ez; ++j) { offs[j] = acc; acc += cnt[j]; }
        offs[Ez] = acc;
    }
    __syncthreads();
    items[offs[e] + r] = tid;
    if (tid <= Ez) off[tid] = offs[tid];
}

// ---------------- kernel 1a: cW partial dots, H split across blocks ----------
#define K1A_ZC 3
#define K1A_HB 48
#define K1A_HC 16
__global__ void k1a_cw(const float* __restrict__ seq, const float* __restrict__ W,
                       const int* __restrict__ turns,
                       const int* __restrict__ off, const int* __restrict__ items,
                       float* __restrict__ pc) {
    int bx = blockIdx.x;
    int e  = bx % Ez;
    int zc = (bx / Ez) % K1A_ZC;
    int hc = bx / (Ez * K1A_ZC);           // 0..15
    int z  = zc * 256 + threadIdx.x;       // 0..767
    int h0 = hc * K1A_HB;
    int off0 = off[e];
    int cnt  = off[e + 1] - off0;
    const float* Wb = W + ((size_t)e * Hz + h0) * Hz + z;
    float w[K1A_HB];
#pragma unroll
    for (int j = 0; j < K1A_HB; ++j) w[j] = Wb[(size_t)j * Hz];

    for (int n = 0; n < cnt; ++n) {
        int i  = items[off0 + n];          // wave-uniform in practice
        int b  = i / Tz;
        int st = turns[2 * i];
        st = min(max(st, 0), Lz - 1);
        const float* c = seq + ((size_t)(b * Lz + st)) * Hz + h0;
        float acc = 0.f;
#pragma unroll
        for (int j = 0; j < K1A_HB; ++j) acc = fmaf(c[j], w[j], acc);
        pc[((size_t)hc * NITEM + i) * Hz + z] = acc;   // disjoint -> plain store
    }
}

// ---------------- kernel 1b: reduce hc partials, v = cW * spanw --------------
__global__ void k1b_v(const float* __restrict__ pc, const float* __restrict__ spanw,
                      const int* __restrict__ midx, float* __restrict__ v) {
    int idx = blockIdx.x * 256 + threadIdx.x;   // 384*768 = 294912
    int i = idx / Hz;
    int z = idx - i * Hz;
    float cw = 0.f;
#pragma unroll
    for (int hc = 0; hc < K1A_HC; ++hc)
        cw += pc[((size_t)hc * NITEM + i) * Hz + z];
    int e = midx[i];
    e = min(max(e, 0), Ez - 1);
    int b = i / Tz, t = i - b * Tz;
    size_t vb = ((size_t)(b * NCOL + t * 2)) * Hz + z;
    v[vb]      = cw * spanw[(e * Hz + z) * 2 + 0];
    v[vb + Hz] = cw * spanw[(e * Hz + z) * 2 + 1];
}

// ---------------- kernel 2: logits GEMM + chunk logsumexp + picked -----------
// r4 diagnosis: latency-bound (VALU 14%, HBM 11%, occupancy 21.8% = 2 blk/CU;
// grid 512 could never exceed 2/CU). This version: 1024 blocks x 64-row chunks,
// 4 blocks/CU, launch_bounds(256,4). Thread = (row r=tid&63, k-quarter
// kq=tid>>6, 16 k-floats). All per-thread state NAMED (rule #20, proven r2->r4
// by WRITE_SIZE 194MB->0.8MB). A staged via XOR-swizzled LDS; V = wave-uniform
// global f4 broadcasts (L2-resident, hidden by 4 waves/SIMD); picked fused.
#define BKP 64               // k floats staged per phase
#define NPH (Hz / BKP)       // 12

typedef float4 F4;

__device__ __forceinline__ float dot16(const float* __restrict__ vp,
                                       F4 a0, F4 a1, F4 a2, F4 a3) {
    const F4* vq = (const F4*)vp;
    F4 q0 = vq[0], q1 = vq[1], q2 = vq[2], q3 = vq[3];
    float s0 = 0.f, s1 = 0.f, s2 = 0.f, s3 = 0.f;
    s0 = fmaf(a0.x, q0.x, s0); s1 = fmaf(a0.y, q0.y, s1);
    s2 = fmaf(a0.z, q0.z, s2); s3 = fmaf(a0.w, q0.w, s3);
    s0 = fmaf(a1.x, q1.x, s0); s1 = fmaf(a1.y, q1.y, s1);
    s2 = fmaf(a1.z, q1.z, s2); s3 = fmaf(a1.w, q1.w, s3);
    s0 = fmaf(a2.x, q2.x, s0); s1 = fmaf(a2.y, q2.y, s1);
    s2 = fmaf(a2.z, q2.z, s2); s3 = fmaf(a2.w, q2.w, s3);
    s0 = fmaf(a3.x, q3.x, s0); s1 = fmaf(a3.y, q3.y, s1);
    s2 = fmaf(a3.z, q3.z, s2); s3 = fmaf(a3.w, q3.w, s3);
    return (s0 + s1) + (s2 + s3);
}

#define C_LIST(X) X(0) X(1) X(2) X(3) X(4) X(5) X(6) X(7) X(8) X(9) X(10) X(11) \
                  X(12) X(13) X(14) X(15) X(16) X(17) X(18) X(19) X(20) X(21) X(22) X(23)

__global__ __launch_bounds__(256, 4)
void k2_logits(const float* __restrict__ seq, const float* __restrict__ v,
               const int* __restrict__ kps,
               float* __restrict__ pm, float* __restrict__ ps,
               float* __restrict__ picked) {
    int bx  = blockIdx.x;
    int b   = bx / NCHUNK;
    int ch  = bx % NCHUNK;
    int l0  = ch * LCHUNK;
    int tid = threadIdx.x;
    int r   = tid & (LCHUNK - 1);                       // row within chunk 0..63
    int kq  = __builtin_amdgcn_readfirstlane(tid >> 6); // k-quarter 0..3

    __shared__ float at[LCHUNK][BKP];        // 16 KB, XOR-swizzled 16B groups
    __shared__ float bufA[LCHUNK][NCOL + 1]; // kq=1 partials (then merged result)
    __shared__ float bufB[LCHUNK][NCOL + 1]; // kq=2 partials
    __shared__ float bufC[LCHUNK][NCOL + 1]; // kq=3 partials
    __shared__ float redm[NCOL][4], reds[NCOL][4];
    __shared__ int   ksafe[NCOL];

    if (tid < NCOL) {
        int t0 = kps[b * NCOL + tid];
        ksafe[tid] = min(max(t0, 0), Lz - 1);
    }

#define DECL_ACC(n) float c##n = 0.f;
    C_LIST(DECL_ACC)
#undef DECL_ACC

    const float* A = seq + ((size_t)b * Lz + l0) * Hz;
    const float* V = v + (size_t)b * NCOL * Hz;

    // staging: thread (rb=tid>>4, cq=tid&15) stages rows rb+16p (p=0..3),
    // 16B group cq, into swizzled slot (cq ^ rb); (rb+16p)&15 == rb -> p-invariant.
    int rb   = tid >> 4;                   // 0..15
    int cq   = tid & 15;
    int slot = ((cq ^ rb) << 2);
    const float* Ab0 = A + (size_t)rb * Hz + (cq << 2);
    float* Sb = &at[0][0] + rb * BKP + slot;          // +1024 floats per p-step (16 rows)

    // phase-invariant LDS read addresses: this thread's 16 A-floats (quarter kq)
    int rx = r & 15;
    const float* arow = &at[r][0];
    const float* ap0 = arow + (((kq * 4 + 0) ^ rx) << 2);
    const float* ap1 = arow + (((kq * 4 + 1) ^ rx) << 2);
    const float* ap2 = arow + (((kq * 4 + 2) ^ rx) << 2);
    const float* ap3 = arow + (((kq * 4 + 3) ^ rx) << 2);

    F4 g0, g1, g2, g3;
#define LOADG(KOFF) do { const float* Ap_ = Ab0 + (KOFF);            \
        g0 = *(const F4*)&Ap_[0 * 16 * Hz];                          \
        g1 = *(const F4*)&Ap_[1 * 16 * Hz];                          \
        g2 = *(const F4*)&Ap_[2 * 16 * Hz];                          \
        g3 = *(const F4*)&Ap_[3 * 16 * Hz]; } while (0)

    LOADG(0);                              // prologue: phase-0 loads

#pragma unroll 1
    for (int ph = 0; ph < NPH; ++ph) {
        __syncthreads();                   // prev compute done reading at
        *(F4*)&Sb[0 * 1024] = g0;  *(F4*)&Sb[1 * 1024] = g1;
        *(F4*)&Sb[2 * 1024] = g2;  *(F4*)&Sb[3 * 1024] = g3;
        __syncthreads();
        if (ph + 1 < NPH) LOADG((ph + 1) * BKP);   // hide HBM under compute

        F4 a0 = *(const F4*)ap0, a1 = *(const F4*)ap1,
           a2 = *(const F4*)ap2, a3 = *(const F4*)ap3;

        const float* Vp = V + ph * BKP + kq * 16;   // wave-uniform
#define DO_COL(n) c##n += dot16(Vp + (n) * Hz, a0, a1, a2, a3);
        C_LIST(DO_COL)
#undef DO_COL
    }
#undef LOADG

    // merge the four k-quarters (rows r held by tid, tid+64, tid+128, tid+192)
    __syncthreads();
    if (kq == 1) {
#define ST_A(n) bufA[r][n] = c##n;
        C_LIST(ST_A)
#undef ST_A
    } else if (kq == 2) {
#define ST_B(n) bufB[r][n] = c##n;
        C_LIST(ST_B)
#undef ST_B
    } else if (kq == 3) {
#define ST_C(n) bufC[r][n] = c##n;
        C_LIST(ST_C)
#undef ST_C
    }
    __syncthreads();
    if (kq == 0) {
        int grow = l0 + r;
#define MG(n) { c##n += bufA[r][n] + bufB[r][n] + bufC[r][n]; bufA[r][n] = c##n; \
                if (ksafe[n] == grow) picked[b * NCOL + (n)] = c##n; }
        C_LIST(MG)
#undef MG
    }
    __syncthreads();

    // chunk logsumexp partials: 96 threads = 24 cols x 4 row-quarters (16 rows each)
    if (tid < 96) {
        int c = tid >> 2, rg = tid & 3;
        float m = bufA[rg * 16][c];
        for (int rr = rg * 16 + 1; rr < rg * 16 + 16; ++rr)
            m = fmaxf(m, bufA[rr][c]);
        float s = 0.f;
        for (int rr = rg * 16; rr < rg * 16 + 16; ++rr)
            s += expf(bufA[rr][c] - m);
        redm[c][rg] = m; reds[c][rg] = s;
    }
    __syncthreads();
    if (tid < NCOL) {
        float m = redm[tid][0];
        for (int j = 1; j < 4; ++j) m = fmaxf(m, redm[tid][j]);
        float s = 0.f;
        for (int j = 0; j < 4; ++j) s += reds[tid][j] * expf(redm[tid][j] - m);
        pm[((size_t)b * NCOL + tid) * NCHUNK + ch] = m;
        ps[((size_t)b * NCOL + tid) * NCHUNK + ch] = s;
    }
}

// ---------------- kernel 4: combine partials -> ce -> masked-mean loss -------
__global__ void k4_final(const int* __restrict__ midx, const int* __restrict__ turns,
                         const int* __restrict__ kps,
                         const float* __restrict__ pm, const float* __restrict__ ps,
                         const float* __restrict__ picked, float* __restrict__ out) {
    int tid = threadIdx.x;                 // 384 threads, one per (b,t)
    int i = tid;
    int b = i / Tz, t = i % Tz;
    int e = midx[i];
    float modm  = (e != EMPTYIDX) ? 1.f : 0.f;
    float tmask = (turns[2 * i] >= 0) ? 1.f : 0.f;
    float ce[2];
#pragma unroll
    for (int k = 0; k < 2; ++k) {
        int c = t * 2 + k;
        const float* pmr = pm + ((size_t)b * NCOL + c) * NCHUNK;
        const float* psr = ps + ((size_t)b * NCOL + c) * NCHUNK;
        float m = pmr[0];
        for (int chn = 1; chn < NCHUNK; ++chn) m = fmaxf(m, pmr[chn]);
        float s = 0.f;
        for (int chn = 0; chn < NCHUNK; ++chn) s += psr[chn] * expf(pmr[chn] - m);
        float lse = m + logf(s);
        int tgt = kps[2 * i + k];
        ce[k] = (tgt >= 0) ? (lse - picked[b * NCOL + c]) : 0.f;
    }
    float contrib = 0.5f * (ce[0] + ce[1]) * modm * tmask;

    __shared__ float wsum[6], wmask[6];
    float sl = contrib, sm = tmask;
    for (int o = 32; o > 0; o >>= 1) {
        sl += __shfl_down(sl, o, 64);
        sm += __shfl_down(sm, o, 64);
    }
    int w = tid >> 6, lane = tid & 63;
    if (lane == 0) { wsum[w] = sl; wmask[w] = sm; }
    __syncthreads();
    if (tid == 0) {
        float a = 0.f, mk = 0.f;
        for (int ww = 0; ww < 6; ++ww) { a += wsum[ww]; mk += wmask[ww]; }
        out[0] = a / mk;
    }
}

extern "C" void kernel_launch(void* const* d_in, const int* in_sizes, int n_in,
                              void* d_out, int out_size, void* d_ws, size_t ws_size,
                              hipStream_t stream) {
    const float* seq   = (const float*)d_in[0];  // (32,2048,768)
    const float* W     = (const float*)d_in[1];  // (7,768,768)
    const float* spanw = (const float*)d_in[2];  // (7,768,2)
    const int*   turns = (const int*)d_in[3];    // (32,12,2)
    const int*   kps   = (const int*)d_in[4];    // (32,12,2)
    const int*   midx  = (const int*)d_in[5];    // (32,12)
    float* out = (float*)d_out;

    char* ws = (char*)d_ws;
    int*   off    = (int*)(ws + 0);                              // 8 ints
    int*   items  = (int*)(ws + 256);                            // 384 ints
    float* pc     = (float*)(ws + 2048);                         // 16*384*768 f32 = 18,874,368 B
    float* v      = (float*)(ws + 2048 + 18874368);              // 32*24*768 f32 =  2,359,296 B
    float* pm     = (float*)(ws + 2048 + 18874368 + 2359296);            // 32*24*32 f32 = 98,304 B
    float* ps     = (float*)(ws + 2048 + 18874368 + 2359296 + 98304);    // 98,304 B
    float* picked = (float*)(ws + 2048 + 18874368 + 2359296 + 196608);   //  1,536 B

    hipLaunchKernelGGL(k0_compact, dim3(1), dim3(NITEM), 0, stream, midx, off, items);
    hipLaunchKernelGGL(k1a_cw, dim3(Ez * K1A_ZC * K1A_HC), dim3(256), 0, stream,
                       seq, W, turns, off, items, pc);
    hipLaunchKernelGGL(k1b_v, dim3((NITEM * Hz) / 256), dim3(256), 0, stream,
                       pc, spanw, midx, v);
    hipLaunchKernelGGL(k2_logits, dim3(Bz * NCHUNK), dim3(256), 0, stream,
                       seq, v, kps, pm, ps, picked);
    hipLaunchKernelGGL(k4_final, dim3(1), dim3(NITEM), 0, stream,
                       midx, turns, kps, pm, ps, picked, out);
}